// Round 4
// baseline (592.189 us; speedup 1.0000x reference)
//
#include <hip/hip_runtime.h>
#include <hip/hip_bf16.h>

// MoE block: H=2048, F=8192, E=8, top-2, T=512 tokens. All inputs fp32.
// Round 4: double-buffered LDS + counted s_waitcnt vmcnt(N) + raw s_barrier
// (T3/T4 2-phase): next tile's global_load_lds DMA stays in flight across the
// barrier; never drain vmcnt(0) in the main loop. Address maps / fragment
// math / epilogues identical to verified round 3.

#define HDIM 2048
#define FDIM 8192
#define NEXP 8
#define NTOK 512
#define MAXT 512

typedef __attribute__((ext_vector_type(8))) short short8;
typedef __attribute__((ext_vector_type(4))) float f32x4;
typedef unsigned int u32;
typedef unsigned short u16;

__device__ __forceinline__ unsigned cvtpk(float lo, float hi) {
    unsigned r;
    asm("v_cvt_pk_bf16_f32 %0, %1, %2" : "=v"(r) : "v"(lo), "v"(hi));
    return r;
}
__device__ __forceinline__ unsigned f2bf1(float f) {
    unsigned u = __builtin_bit_cast(unsigned, f);
    return (u + 0x7FFFu + ((u >> 16) & 1u)) >> 16;
}
__device__ __forceinline__ void gload16(const void* g, void* l) {
    __builtin_amdgcn_global_load_lds((const __attribute__((address_space(1))) u32*)g,
                                     (__attribute__((address_space(3))) u32*)l, 16, 0, 0);
}

// A tile (bf16 [128 rows][64 k]) byte offset, XOR-swizzled; matches the
// linear DMA layout with source chunk pre-XOR (chunk ^= row&7).
#define A_OFF(r, k) (((((r)*64) + (k)) * 2) ^ ((((r) & 7)) << 4))

// ---------------------------------------------------------------- router
__global__ void moe_router(const float* __restrict__ x, const float* __restrict__ Wg,
                           int* __restrict__ counts, int* __restrict__ tok_id,
                           float* __restrict__ tok_w) {
    const int t = blockIdx.x;
    const int lane = threadIdx.x;
    const float* xr = x + (size_t)t * HDIM;
    float acc[8];
    #pragma unroll
    for (int e = 0; e < 8; ++e) acc[e] = 0.f;
    #pragma unroll 4
    for (int i = 0; i < HDIM / 64; ++i) {
        int h = lane + i * 64;
        float xv = xr[h];
        const float4* wr = (const float4*)(Wg + (size_t)h * 8);
        float4 wa = wr[0], wb = wr[1];
        acc[0] += xv * wa.x; acc[1] += xv * wa.y; acc[2] += xv * wa.z; acc[3] += xv * wa.w;
        acc[4] += xv * wb.x; acc[5] += xv * wb.y; acc[6] += xv * wb.z; acc[7] += xv * wb.w;
    }
    #pragma unroll
    for (int off = 32; off >= 1; off >>= 1) {
        #pragma unroll
        for (int e = 0; e < 8; ++e) acc[e] += __shfl_xor(acc[e], off);
    }
    if (lane == 0) {
        int e0 = 0;
        #pragma unroll
        for (int e = 1; e < 8; ++e) if (acc[e] > acc[e0]) e0 = e;
        int e1 = (e0 == 0) ? 1 : 0;
        #pragma unroll
        for (int e = 0; e < 8; ++e) if (e != e0 && acc[e] > acc[e1]) e1 = e;
        float w0 = 1.f / (1.f + __expf(acc[e1] - acc[e0]));
        float w1 = 1.f - w0;
        int s0 = atomicAdd(&counts[e0], 1);
        tok_id[e0 * MAXT + s0] = t; tok_w[e0 * MAXT + s0] = w0;
        int s1 = atomicAdd(&counts[e1], 1);
        tok_id[e1 * MAXT + s1] = t; tok_w[e1 * MAXT + s1] = w1;
    }
}

__global__ void moe_scan(const int* __restrict__ counts, int* __restrict__ offsets) {
    if (threadIdx.x == 0) {
        int a = 0;
        for (int e = 0; e < NEXP; ++e) { offsets[e] = a; a += counts[e]; }
    }
}

// ------------------------------------------------------------- x -> bf16
__global__ void moe_xcvt(const float* __restrict__ x, u16* __restrict__ xbf) {
    const int i = (blockIdx.x * 256 + threadIdx.x) * 8;
    float4 a = *(const float4*)(x + i);
    float4 b = *(const float4*)(x + i + 4);
    uint4 q;
    q.x = cvtpk(a.x, a.y); q.y = cvtpk(a.z, a.w);
    q.z = cvtpk(b.x, b.y); q.w = cvtpk(b.z, b.w);
    *(uint4*)(xbf + i) = q;
}

// B-fragment build: weights fp32 in LDS as [k][64 n], dword slot
// n' = n ^ (((k>>3)&1)<<4). 8x ds_read_b32 (2-way conflict = free) + cvt_pk.
__device__ __forceinline__ short8 bfrag(const float* sB, int kbase, int nsw) {
    const float* p = sB + kbase * 64 + nsw;
    float f[8];
    #pragma unroll
    for (int j = 0; j < 8; ++j) f[j] = p[j * 64];
    uint4 q;
    q.x = cvtpk(f[0], f[1]); q.y = cvtpk(f[2], f[3]);
    q.z = cvtpk(f[4], f[5]); q.w = cvtpk(f[6], f[7]);
    return __builtin_bit_cast(short8, q);
}

// ---------------------------------------------------------------- GEMM1
// h[slot,n] = relu(x W1) * (x W3), bf16 out. BM=128 BN=64 BK=64, waves 2x2.
// Double-buffered, counted vmcnt(12).
__global__ __launch_bounds__(256, 1)
void moe_gemm1(const u16* __restrict__ xbf, const float* __restrict__ W1,
               const float* __restrict__ W3, const int* __restrict__ counts,
               const int* __restrict__ offsets, const int* __restrict__ tok_id,
               u16* __restrict__ hbuf) {
    const int nt = blockIdx.x, mt = blockIdx.y, e = blockIdx.z;
    const int cnt = counts[e];
    if (mt * 128 >= cnt) return;
    const int n0 = nt * 64;
    const int tid = threadIdx.x;
    const int w = tid >> 6, l = tid & 63;

    __shared__ __align__(16) unsigned char sA[2][128 * 64 * 2];
    __shared__ __align__(16) float sB1[2][64 * 64];
    __shared__ __align__(16) float sB3[2][64 * 64];

    // A staging map (DMA): lane covers row = w*32+p*8+(l>>3), chunk l&7.
    const int ar = (l >> 3), ac = l & 7;
    const u16* asrc[4];
    #pragma unroll
    for (int p = 0; p < 4; ++p) {
        int row = w * 32 + p * 8 + ar;
        int slot = mt * 128 + row;
        int tok = tok_id[e * MAXT + (slot < cnt ? slot : cnt - 1)];
        asrc[p] = xbf + (size_t)tok * HDIM + (ac ^ (row & 7)) * 8;
    }
    // B staging map: krow = w*16+p*4+(l>>4), chunk c4 = l&15 (src XOR k-octet).
    const int kr = (l >> 4), c4 = l & 15;
    const size_t wstride = (size_t)HDIM * FDIM;
    size_t bsrc[4];
    #pragma unroll
    for (int p = 0; p < 4; ++p) {
        int krow = w * 16 + p * 4 + kr;
        bsrc[p] = (size_t)e * wstride + (size_t)krow * FDIM + n0 +
                  (size_t)((c4 ^ (((krow >> 3) & 1) << 2)) * 4);
    }

    const int wr = (w >> 1) * 64, wc = (w & 1) * 32;
    const int lr = l & 15, lg = l >> 4;
    const int lk = lg * 8;
    const int g1 = lg & 1;

    f32x4 acc1[4][2], acc3[4][2];
    #pragma unroll
    for (int mi = 0; mi < 4; ++mi)
        #pragma unroll
        for (int ni = 0; ni < 2; ++ni) { acc1[mi][ni] = (f32x4)0.f; acc3[mi][ni] = (f32x4)0.f; }

    #define STAGE1(buf, kt)                                                              \
        _Pragma("unroll")                                                                \
        for (int p = 0; p < 4; ++p) {                                                    \
            gload16(asrc[p] + (kt) * 64, &sA[buf][(w * 32 + p * 8) * 128]);              \
            gload16(W1 + bsrc[p] + (size_t)(kt) * 64 * FDIM, &sB1[buf][(w * 16 + p * 4) * 64]); \
            gload16(W3 + bsrc[p] + (size_t)(kt) * 64 * FDIM, &sB3[buf][(w * 16 + p * 4) * 64]); \
        }

    STAGE1(0, 0);
    for (int kt = 0; kt < HDIM / 64; ++kt) {
        const int cur = kt & 1;
        if (kt + 1 < HDIM / 64) {
            STAGE1(cur ^ 1, kt + 1);
            asm volatile("s_waitcnt vmcnt(12)" ::: "memory");
        } else {
            asm volatile("s_waitcnt vmcnt(0)" ::: "memory");
        }
        __builtin_amdgcn_s_barrier();
        asm volatile("" ::: "memory");
        #pragma unroll
        for (int ks = 0; ks < 2; ++ks) {
            const int kk = ks * 32 + lk;
            short8 a[4];
            #pragma unroll
            for (int mi = 0; mi < 4; ++mi)
                a[mi] = *(const short8*)&sA[cur][A_OFF(wr + mi * 16 + lr, kk)];
            #pragma unroll
            for (int ni = 0; ni < 2; ++ni) {
                const int nsw = (wc + ni * 16 + lr) ^ (g1 << 4);
                short8 b1 = bfrag(sB1[cur], kk, nsw);
                short8 b3 = bfrag(sB3[cur], kk, nsw);
                #pragma unroll
                for (int mi = 0; mi < 4; ++mi) {
                    acc1[mi][ni] = __builtin_amdgcn_mfma_f32_16x16x32_bf16(a[mi], b1, acc1[mi][ni], 0, 0, 0);
                    acc3[mi][ni] = __builtin_amdgcn_mfma_f32_16x16x32_bf16(a[mi], b3, acc3[mi][ni], 0, 0, 0);
                }
            }
        }
        asm volatile("" ::: "memory");
        __builtin_amdgcn_s_barrier();
    }
    // ---- epilogue: h = relu(h1)*h3 -> bf16 compact rows
    const int hbase = offsets[e] + mt * 128;
    #pragma unroll
    for (int mi = 0; mi < 4; ++mi)
        #pragma unroll
        for (int ni = 0; ni < 2; ++ni)
            #pragma unroll
            for (int r = 0; r < 4; ++r) {
                int rl = wr + mi * 16 + (l >> 4) * 4 + r;
                int sl = mt * 128 + rl;
                if (sl < cnt) {
                    float v1 = acc1[mi][ni][r];
                    v1 = v1 > 0.f ? v1 : 0.f;
                    float hv = v1 * acc3[mi][ni][r];
                    hbuf[(size_t)(hbase + rl) * FDIM + (n0 + wc + ni * 16 + lr)] =
                        (u16)f2bf1(hv);
                }
            }
}

// ---------------------------------------------------------------- GEMM2
// out[t,n] += w * (h W2). BM=128 BN=64 BK=64, split-K x4. Double-buffered,
// counted vmcnt(8).
__global__ __launch_bounds__(256, 2)
void moe_gemm2(const u16* __restrict__ hbuf, const float* __restrict__ W2,
               const int* __restrict__ counts, const int* __restrict__ offsets,
               const int* __restrict__ tok_id, const float* __restrict__ tok_w,
               float* __restrict__ out) {
    const int nt = blockIdx.x, e = blockIdx.z;
    const int mt = blockIdx.y & 3, ksp = blockIdx.y >> 2;
    const int cnt = counts[e];
    if (mt * 128 >= cnt) return;
    const int n0 = nt * 64;
    const int tid = threadIdx.x;
    const int w = tid >> 6, l = tid & 63;

    __shared__ __align__(16) unsigned char sA[2][128 * 64 * 2];
    __shared__ __align__(16) float sB[2][64 * 64];

    const int ar = (l >> 3), ac = l & 7;
    const u16* asrc[4];
    #pragma unroll
    for (int p = 0; p < 4; ++p) {
        int row = w * 32 + p * 8 + ar;
        int hrow = offsets[e] + mt * 128 + row;  // hbuf padded; tail masked in epilogue
        asrc[p] = hbuf + (size_t)hrow * FDIM + ksp * 2048 + (ac ^ (row & 7)) * 8;
    }
    const int kr = (l >> 4), c4 = l & 15;
    size_t bsrc[4];
    #pragma unroll
    for (int p = 0; p < 4; ++p) {
        int krow = w * 16 + p * 4 + kr;
        bsrc[p] = (size_t)e * ((size_t)FDIM * HDIM) + (size_t)(ksp * 2048 + krow) * HDIM +
                  n0 + (size_t)((c4 ^ (((krow >> 3) & 1) << 2)) * 4);
    }

    const int wr = (w >> 1) * 64, wc = (w & 1) * 32;
    const int lr = l & 15, lg = l >> 4;
    const int lk = lg * 8;
    const int g1 = lg & 1;

    f32x4 acc[4][2];
    #pragma unroll
    for (int mi = 0; mi < 4; ++mi)
        #pragma unroll
        for (int ni = 0; ni < 2; ++ni) acc[mi][ni] = (f32x4)0.f;

    #define STAGE2(buf, kt)                                                          \
        _Pragma("unroll")                                                            \
        for (int p = 0; p < 4; ++p) {                                                \
            gload16(asrc[p] + (kt) * 64, &sA[buf][(w * 32 + p * 8) * 128]);          \
            gload16(W2 + bsrc[p] + (size_t)(kt) * 64 * HDIM, &sB[buf][(w * 16 + p * 4) * 64]); \
        }

    STAGE2(0, 0);
    for (int kt = 0; kt < 32; ++kt) {
        const int cur = kt & 1;
        if (kt + 1 < 32) {
            STAGE2(cur ^ 1, kt + 1);
            asm volatile("s_waitcnt vmcnt(8)" ::: "memory");
        } else {
            asm volatile("s_waitcnt vmcnt(0)" ::: "memory");
        }
        __builtin_amdgcn_s_barrier();
        asm volatile("" ::: "memory");
        #pragma unroll
        for (int ks = 0; ks < 2; ++ks) {
            const int kk = ks * 32 + lk;
            short8 a[4];
            #pragma unroll
            for (int mi = 0; mi < 4; ++mi)
                a[mi] = *(const short8*)&sA[cur][A_OFF(wr + mi * 16 + lr, kk)];
            #pragma unroll
            for (int ni = 0; ni < 2; ++ni) {
                const int nsw = (wc + ni * 16 + lr) ^ (g1 << 4);
                short8 b = bfrag(sB[cur], kk, nsw);
                #pragma unroll
                for (int mi = 0; mi < 4; ++mi)
                    acc[mi][ni] = __builtin_amdgcn_mfma_f32_16x16x32_bf16(a[mi], b, acc[mi][ni], 0, 0, 0);
            }
        }
        asm volatile("" ::: "memory");
        __builtin_amdgcn_s_barrier();
    }
    // ---- epilogue: scaled partial scatter-add
    #pragma unroll
    for (int mi = 0; mi < 4; ++mi)
        #pragma unroll
        for (int ni = 0; ni < 2; ++ni)
            #pragma unroll
            for (int r = 0; r < 4; ++r) {
                int rl = wr + mi * 16 + (l >> 4) * 4 + r;
                int sl = mt * 128 + rl;
                if (sl < cnt) {
                    int tk = tok_id[e * MAXT + sl];
                    float wgt = tok_w[e * MAXT + sl];
                    atomicAdd(&out[(size_t)tk * HDIM + (n0 + wc + ni * 16 + lr)],
                              wgt * acc[mi][ni][r]);
                }
            }
}

// ---------------------------------------------------------------- launch
extern "C" void kernel_launch(void* const* d_in, const int* in_sizes, int n_in,
                              void* d_out, int out_size, void* d_ws, size_t ws_size,
                              hipStream_t stream) {
    const float* x  = (const float*)d_in[0];
    const float* Wg = (const float*)d_in[1];
    const float* W1 = (const float*)d_in[2];
    const float* W2 = (const float*)d_in[3];
    const float* W3 = (const float*)d_in[4];
    float* out = (float*)d_out;

    char* ws = (char*)d_ws;
    int*   counts  = (int*)(ws + 0);
    int*   offsets = (int*)(ws + 32);
    int*   tok_id  = (int*)(ws + 64);
    float* tok_w   = (float*)(ws + 64 + NEXP * MAXT * 4);
    u16*   xbf     = (u16*)(ws + 65536);                            // 512x2048 bf16 = 2MB
    u16*   hbuf    = (u16*)(ws + 65536 + (size_t)NTOK * HDIM * 2);  // (1024+128)x8192 bf16

    hipMemsetAsync(ws, 0, 64, stream);
    hipMemsetAsync(d_out, 0, (size_t)out_size * sizeof(float), stream);

    moe_router<<<NTOK, 64, 0, stream>>>(x, Wg, counts, tok_id, tok_w);
    moe_scan<<<1, 64, 0, stream>>>(counts, offsets);
    moe_xcvt<<<NTOK * HDIM / (256 * 8), 256, 0, stream>>>(x, xbf);
    moe_gemm1<<<dim3(FDIM / 64, 4, NEXP), 256, 0, stream>>>(xbf, W1, W3, counts, offsets, tok_id, hbuf);
    moe_gemm2<<<dim3(HDIM / 64, 16, NEXP), 256, 0, stream>>>(hbuf, W2, counts, offsets, tok_id, tok_w, out);
}

// Round 7
// 523.140 us; speedup vs baseline: 1.1320x; 1.1320x over previous
//
#include <hip/hip_runtime.h>
#include <hip/hip_bf16.h>

// MoE block: H=2048, F=8192, E=8, top-2, T=512 tokens. All inputs fp32.
// Round 7: BK=32 dbuf + counted vmcnt rebuilt from proven parts only.
//  - A staged via registers + padded ds_write (identity layout [128][40]u16,
//    80B rows: <=2-way banks on write and on b128 read). No DMA-dest swizzle.
//  - B staged via global_load_lds with the round-3/4-proven octet-XOR map.
//  - Pipeline: vmcnt(A) -> ds_write A -> issue next A+B (order pinned) ->
//    vmcnt(B) lgkmcnt(0) -> s_barrier -> MFMA -> s_barrier.
// LDS: gemm1 52KB (3 blocks/CU), gemm2 36KB (4 blocks/CU).

#define HDIM 2048
#define FDIM 8192
#define NEXP 8
#define NTOK 512
#define MAXT 512

typedef __attribute__((ext_vector_type(8))) short short8;
typedef __attribute__((ext_vector_type(4))) float f32x4;
typedef unsigned int u32;
typedef unsigned short u16;

__device__ __forceinline__ unsigned cvtpk(float lo, float hi) {
    unsigned r;
    asm("v_cvt_pk_bf16_f32 %0, %1, %2" : "=v"(r) : "v"(lo), "v"(hi));
    return r;
}
__device__ __forceinline__ unsigned f2bf1(float f) {
    unsigned u = __builtin_bit_cast(unsigned, f);
    return (u + 0x7FFFu + ((u >> 16) & 1u)) >> 16;
}
__device__ __forceinline__ void gload16(const void* g, void* l) {
    __builtin_amdgcn_global_load_lds((const __attribute__((address_space(1))) u32*)g,
                                     (__attribute__((address_space(3))) u32*)l, 16, 0, 0);
}
#define SBAR() __builtin_amdgcn_sched_barrier(0)

// ---------------------------------------------------------------- router
__global__ void moe_router(const float* __restrict__ x, const float* __restrict__ Wg,
                           int* __restrict__ counts, int* __restrict__ tok_id,
                           float* __restrict__ tok_w) {
    const int t = blockIdx.x;
    const int lane = threadIdx.x;
    const float* xr = x + (size_t)t * HDIM;
    float acc[8];
    #pragma unroll
    for (int e = 0; e < 8; ++e) acc[e] = 0.f;
    #pragma unroll 4
    for (int i = 0; i < HDIM / 64; ++i) {
        int h = lane + i * 64;
        float xv = xr[h];
        const float4* wr = (const float4*)(Wg + (size_t)h * 8);
        float4 wa = wr[0], wb = wr[1];
        acc[0] += xv * wa.x; acc[1] += xv * wa.y; acc[2] += xv * wa.z; acc[3] += xv * wa.w;
        acc[4] += xv * wb.x; acc[5] += xv * wb.y; acc[6] += xv * wb.z; acc[7] += xv * wb.w;
    }
    #pragma unroll
    for (int off = 32; off >= 1; off >>= 1) {
        #pragma unroll
        for (int e = 0; e < 8; ++e) acc[e] += __shfl_xor(acc[e], off);
    }
    if (lane == 0) {
        int e0 = 0;
        #pragma unroll
        for (int e = 1; e < 8; ++e) if (acc[e] > acc[e0]) e0 = e;
        int e1 = (e0 == 0) ? 1 : 0;
        #pragma unroll
        for (int e = 0; e < 8; ++e) if (e != e0 && acc[e] > acc[e1]) e1 = e;
        float w0 = 1.f / (1.f + __expf(acc[e1] - acc[e0]));
        float w1 = 1.f - w0;
        int s0 = atomicAdd(&counts[e0], 1);
        tok_id[e0 * MAXT + s0] = t; tok_w[e0 * MAXT + s0] = w0;
        int s1 = atomicAdd(&counts[e1], 1);
        tok_id[e1 * MAXT + s1] = t; tok_w[e1 * MAXT + s1] = w1;
    }
}

__global__ void moe_scan(const int* __restrict__ counts, int* __restrict__ offsets) {
    if (threadIdx.x == 0) {
        int a = 0;
        for (int e = 0; e < NEXP; ++e) { offsets[e] = a; a += counts[e]; }
    }
}

// ------------------------------------------------------------- x -> bf16
__global__ void moe_xcvt(const float* __restrict__ x, u16* __restrict__ xbf) {
    const int i = (blockIdx.x * 256 + threadIdx.x) * 8;
    float4 a = *(const float4*)(x + i);
    float4 b = *(const float4*)(x + i + 4);
    uint4 q;
    q.x = cvtpk(a.x, a.y); q.y = cvtpk(a.z, a.w);
    q.z = cvtpk(b.x, b.y); q.w = cvtpk(b.z, b.w);
    *(uint4*)(xbf + i) = q;
}

// B-fragment build: weights fp32 in LDS as [32 k][64 n], dword slot
// n' = n ^ (((k>>3)&1)<<4). 8x ds_read_b32 (2-way = free) + 4 cvt_pk.
// Byte-identical to the round-3/4-proven map.
__device__ __forceinline__ short8 bfrag(const float* sB, int kbase, int nsw) {
    const float* p = sB + kbase * 64 + nsw;
    float f[8];
    #pragma unroll
    for (int j = 0; j < 8; ++j) f[j] = p[j * 64];
    uint4 q;
    q.x = cvtpk(f[0], f[1]); q.y = cvtpk(f[2], f[3]);
    q.z = cvtpk(f[4], f[5]); q.w = cvtpk(f[6], f[7]);
    return __builtin_bit_cast(short8, q);
}

// ---------------------------------------------------------------- GEMM1
// h[slot,n] = relu(x W1) * (x W3), bf16 out. BM=128 BN=64 BK=32, waves 2x2.
__global__ __launch_bounds__(256, 2)
void moe_gemm1(const u16* __restrict__ xbf, const float* __restrict__ W1,
               const float* __restrict__ W3, const int* __restrict__ counts,
               const int* __restrict__ offsets, const int* __restrict__ tok_id,
               u16* __restrict__ hbuf) {
    const int nt = blockIdx.x, mt = blockIdx.y, e = blockIdx.z;
    const int cnt = counts[e];
    if (mt * 128 >= cnt) return;
    const int n0 = nt * 64;
    const int tid = threadIdx.x;
    const int w = tid >> 6, l = tid & 63;

    __shared__ __align__(16) u16 sApad[2][128 * 40];   // padded bf16, identity layout
    __shared__ __align__(16) float sB1[2][2048];       // fp32 [32][64] oct-XOR'd
    __shared__ __align__(16) float sB3[2][2048];

    // ---- A reg-staging: thread covers row tid>>1, k-half (tid&1)*16.
    const int arow = tid >> 1;
    const int akc = (tid & 1) * 16;
    const int aslot = mt * 128 + arow;
    const int atok = tok_id[e * MAXT + (aslot < cnt ? aslot : cnt - 1)];
    const u16* areg_src = xbf + (size_t)atok * HDIM + akc;

    // ---- B DMA map (proven): instr i covers krow = i*16 + w*4 + (l>>4),
    // chunk c4 = l&15; source chunk pre-XOR'd by k-octet bit.
    const int kr = l >> 4, c4 = l & 15;
    const size_t wstride = (size_t)HDIM * FDIM;
    const float* b1p[2]; const float* b3p[2];
    #pragma unroll
    for (int i = 0; i < 2; ++i) {
        int krow = i * 16 + w * 4 + kr;
        size_t off = (size_t)e * wstride + (size_t)krow * FDIM + n0 +
                     (size_t)((c4 ^ (((krow >> 3) & 1) << 2)) * 4);
        b1p[i] = W1 + off; b3p[i] = W3 + off;
    }

    const int wr = (w >> 1) * 64, wc = (w & 1) * 32;
    const int lr = l & 15, lg = l >> 4;
    const int lk = lg * 8;
    const int g1 = lg & 1;

    f32x4 acc1[4][2], acc3[4][2];
    #pragma unroll
    for (int mi = 0; mi < 4; ++mi)
        #pragma unroll
        for (int ni = 0; ni < 2; ++ni) { acc1[mi][ni] = (f32x4)0.f; acc3[mi][ni] = (f32x4)0.f; }

    uint4 a0, a1;
    #define ALOAD1(kt) { const u16* s_ = areg_src + (kt) * 32;                 \
                         a0 = *(const uint4*)s_; a1 = *(const uint4*)(s_ + 8); }
    #define AWRITE1(buf) { *(uint4*)&sApad[buf][arow * 40 + akc] = a0;         \
                           *(uint4*)&sApad[buf][arow * 40 + akc + 8] = a1; }
    #define BSTAGE1(buf, kt)                                                   \
        _Pragma("unroll")                                                      \
        for (int i = 0; i < 2; ++i) {                                          \
            gload16(b1p[i] + (size_t)(kt) * 32 * FDIM, &sB1[buf][(i * 16 + w * 4) * 64]); \
            gload16(b3p[i] + (size_t)(kt) * 32 * FDIM, &sB3[buf][(i * 16 + w * 4) * 64]); \
        }

    ALOAD1(0);                 // 2 vmem
    SBAR();
    BSTAGE1(0, 0);             // 4 vmem
    SBAR();
    for (int kt = 0; kt < HDIM / 32; ++kt) {
        const int cur = kt & 1;
        asm volatile("s_waitcnt vmcnt(4)" ::: "memory");   // A(kt) regs ready
        SBAR();
        AWRITE1(cur);
        SBAR();
        if (kt + 1 < HDIM / 32) {
            ALOAD1(kt + 1);
            SBAR();
            BSTAGE1(cur ^ 1, kt + 1);
            SBAR();
            asm volatile("s_waitcnt vmcnt(6) lgkmcnt(0)" ::: "memory"); // B(kt) done, A write visible
        } else {
            asm volatile("s_waitcnt vmcnt(0) lgkmcnt(0)" ::: "memory");
        }
        SBAR();
        __builtin_amdgcn_s_barrier();
        SBAR();
        short8 a[4];
        #pragma unroll
        for (int mi = 0; mi < 4; ++mi)
            a[mi] = *(const short8*)&sApad[cur][(wr + mi * 16 + lr) * 40 + lk];
        #pragma unroll
        for (int ni = 0; ni < 2; ++ni) {
            const int nsw = (wc + ni * 16 + lr) ^ (g1 << 4);
            short8 b1 = bfrag(sB1[cur], lk, nsw);
            short8 b3 = bfrag(sB3[cur], lk, nsw);
            #pragma unroll
            for (int mi = 0; mi < 4; ++mi) {
                acc1[mi][ni] = __builtin_amdgcn_mfma_f32_16x16x32_bf16(a[mi], b1, acc1[mi][ni], 0, 0, 0);
                acc3[mi][ni] = __builtin_amdgcn_mfma_f32_16x16x32_bf16(a[mi], b3, acc3[mi][ni], 0, 0, 0);
            }
        }
        SBAR();
        __builtin_amdgcn_s_barrier();
        SBAR();
    }
    // ---- epilogue: h = relu(h1)*h3 -> bf16 compact rows
    const int hbase = offsets[e] + mt * 128;
    #pragma unroll
    for (int mi = 0; mi < 4; ++mi)
        #pragma unroll
        for (int ni = 0; ni < 2; ++ni)
            #pragma unroll
            for (int r = 0; r < 4; ++r) {
                int rl = wr + mi * 16 + (l >> 4) * 4 + r;
                int sl = mt * 128 + rl;
                if (sl < cnt) {
                    float v1 = acc1[mi][ni][r];
                    v1 = v1 > 0.f ? v1 : 0.f;
                    float hv = v1 * acc3[mi][ni][r];
                    hbuf[(size_t)(hbase + rl) * FDIM + (n0 + wc + ni * 16 + lr)] =
                        (u16)f2bf1(hv);
                }
            }
}

// ---------------------------------------------------------------- GEMM2
// out[t,n] += w * (h W2). BM=128 BN=64 BK=32, split-K x4.
__global__ __launch_bounds__(256, 2)
void moe_gemm2(const u16* __restrict__ hbuf, const float* __restrict__ W2,
               const int* __restrict__ counts, const int* __restrict__ offsets,
               const int* __restrict__ tok_id, const float* __restrict__ tok_w,
               float* __restrict__ out) {
    const int nt = blockIdx.x, e = blockIdx.z;
    const int mt = blockIdx.y & 3, ksp = blockIdx.y >> 2;
    const int cnt = counts[e];
    if (mt * 128 >= cnt) return;
    const int n0 = nt * 64;
    const int tid = threadIdx.x;
    const int w = tid >> 6, l = tid & 63;

    __shared__ __align__(16) u16 sApad[2][128 * 40];
    __shared__ __align__(16) float sB[2][2048];

    const int arow = tid >> 1;
    const int akc = (tid & 1) * 16;
    const int hrow = offsets[e] + mt * 128 + arow;   // hbuf padded; tail masked in epilogue
    const u16* areg_src = hbuf + (size_t)hrow * FDIM + ksp * 2048 + akc;

    const int kr = l >> 4, c4 = l & 15;
    const float* b2p[2];
    #pragma unroll
    for (int i = 0; i < 2; ++i) {
        int krow = i * 16 + w * 4 + kr;
        b2p[i] = W2 + (size_t)e * ((size_t)FDIM * HDIM) + (size_t)(ksp * 2048 + krow) * HDIM +
                 n0 + (size_t)((c4 ^ (((krow >> 3) & 1) << 2)) * 4);
    }

    const int wr = (w >> 1) * 64, wc = (w & 1) * 32;
    const int lr = l & 15, lg = l >> 4;
    const int lk = lg * 8;
    const int g1 = lg & 1;

    f32x4 acc[4][2];
    #pragma unroll
    for (int mi = 0; mi < 4; ++mi)
        #pragma unroll
        for (int ni = 0; ni < 2; ++ni) acc[mi][ni] = (f32x4)0.f;

    uint4 a0, a1;
    #define ALOAD2(kt) { const u16* s_ = areg_src + (kt) * 32;                 \
                         a0 = *(const uint4*)s_; a1 = *(const uint4*)(s_ + 8); }
    #define AWRITE2(buf) { *(uint4*)&sApad[buf][arow * 40 + akc] = a0;         \
                           *(uint4*)&sApad[buf][arow * 40 + akc + 8] = a1; }
    #define BSTAGE2(buf, kt)                                                   \
        _Pragma("unroll")                                                      \
        for (int i = 0; i < 2; ++i)                                            \
            gload16(b2p[i] + (size_t)(kt) * 32 * HDIM, &sB[buf][(i * 16 + w * 4) * 64]);

    ALOAD2(0);                 // 2 vmem
    SBAR();
    BSTAGE2(0, 0);             // 2 vmem
    SBAR();
    for (int kt = 0; kt < 64; ++kt) {
        const int cur = kt & 1;
        asm volatile("s_waitcnt vmcnt(2)" ::: "memory");   // A(kt) regs ready
        SBAR();
        AWRITE2(cur);
        SBAR();
        if (kt + 1 < 64) {
            ALOAD2(kt + 1);
            SBAR();
            BSTAGE2(cur ^ 1, kt + 1);
            SBAR();
            asm volatile("s_waitcnt vmcnt(4) lgkmcnt(0)" ::: "memory"); // B(kt) done
        } else {
            asm volatile("s_waitcnt vmcnt(0) lgkmcnt(0)" ::: "memory");
        }
        SBAR();
        __builtin_amdgcn_s_barrier();
        SBAR();
        short8 a[4];
        #pragma unroll
        for (int mi = 0; mi < 4; ++mi)
            a[mi] = *(const short8*)&sApad[cur][(wr + mi * 16 + lr) * 40 + lk];
        #pragma unroll
        for (int ni = 0; ni < 2; ++ni) {
            const int nsw = (wc + ni * 16 + lr) ^ (g1 << 4);
            short8 b = bfrag(sB[cur], lk, nsw);
            #pragma unroll
            for (int mi = 0; mi < 4; ++mi)
                acc[mi][ni] = __builtin_amdgcn_mfma_f32_16x16x32_bf16(a[mi], b, acc[mi][ni], 0, 0, 0);
        }
        SBAR();
        __builtin_amdgcn_s_barrier();
        SBAR();
    }
    // ---- epilogue: scaled partial scatter-add
    #pragma unroll
    for (int mi = 0; mi < 4; ++mi)
        #pragma unroll
        for (int ni = 0; ni < 2; ++ni)
            #pragma unroll
            for (int r = 0; r < 4; ++r) {
                int rl = wr + mi * 16 + (l >> 4) * 4 + r;
                int sl = mt * 128 + rl;
                if (sl < cnt) {
                    int tk = tok_id[e * MAXT + sl];
                    float wgt = tok_w[e * MAXT + sl];
                    atomicAdd(&out[(size_t)tk * HDIM + (n0 + wc + ni * 16 + lr)],
                              wgt * acc[mi][ni][r]);
                }
            }
}

// ---------------------------------------------------------------- launch
extern "C" void kernel_launch(void* const* d_in, const int* in_sizes, int n_in,
                              void* d_out, int out_size, void* d_ws, size_t ws_size,
                              hipStream_t stream) {
    const float* x  = (const float*)d_in[0];
    const float* Wg = (const float*)d_in[1];
    const float* W1 = (const float*)d_in[2];
    const float* W2 = (const float*)d_in[3];
    const float* W3 = (const float*)d_in[4];
    float* out = (float*)d_out;

    char* ws = (char*)d_ws;
    int*   counts  = (int*)(ws + 0);
    int*   offsets = (int*)(ws + 32);
    int*   tok_id  = (int*)(ws + 64);
    float* tok_w   = (float*)(ws + 64 + NEXP * MAXT * 4);
    u16*   xbf     = (u16*)(ws + 65536);                            // 512x2048 bf16 = 2MB
    u16*   hbuf    = (u16*)(ws + 65536 + (size_t)NTOK * HDIM * 2);  // (1024+128)x8192 bf16

    hipMemsetAsync(ws, 0, 64, stream);
    hipMemsetAsync(d_out, 0, (size_t)out_size * sizeof(float), stream);

    moe_router<<<NTOK, 64, 0, stream>>>(x, Wg, counts, tok_id, tok_w);
    moe_scan<<<1, 64, 0, stream>>>(counts, offsets);
    moe_xcvt<<<NTOK * HDIM / (256 * 8), 256, 0, stream>>>(x, xbf);
    moe_gemm1<<<dim3(FDIM / 64, 4, NEXP), 256, 0, stream>>>(xbf, W1, W3, counts, offsets, tok_id, hbuf);
    moe_gemm2<<<dim3(HDIM / 64, 16, NEXP), 256, 0, stream>>>(hbuf, W2, counts, offsets, tok_id, tok_w, out);
}